// Round 5
// baseline (897.039 us; speedup 1.0000x reference)
//
#include <hip/hip_runtime.h>

#define H_ 2048
#define E_ 32
#define KSEL 4
#define M_ 1408
#define I_ 8192
#define T_ 2048

typedef __bf16 bf16;
typedef bf16 bf16x8 __attribute__((ext_vector_type(8)));
typedef float f32x4 __attribute__((ext_vector_type(4)));
typedef unsigned short u16x8 __attribute__((ext_vector_type(8)));

static __device__ __forceinline__ unsigned short bfb(float f) {
  return __builtin_bit_cast(unsigned short, (bf16)f);
}

static __device__ __forceinline__ void gload_lds16(const void* g, void* l) {
  __builtin_amdgcn_global_load_lds((const __attribute__((address_space(1))) void*)g,
                                   (__attribute__((address_space(3))) void*)l, 16, 0, 0);
}

static __device__ __forceinline__ float silu_f(float v) {
  return v / (1.f + __expf(-v));
}

static __device__ __forceinline__ void wave_argmax(float& v, int& vi) {
  #pragma unroll
  for (int off = 32; off >= 1; off >>= 1) {
    float ov = __shfl_xor(v, off);
    int   oi = __shfl_xor(vi, off);
    if (ov > v || (ov == v && oi < vi)) { v = ov; vi = oi; }
  }
}

// ---------------- prep: zero out[T,H] and counts ----------------
__global__ __launch_bounds__(256) void prep_k(float* __restrict__ out, int* __restrict__ counts) {
  size_t i = ((size_t)blockIdx.x * 256 + threadIdx.x) * 4;
  *(float4*)(out + i) = make_float4(0.f, 0.f, 0.f, 0.f);
  if (blockIdx.x == 0 && threadIdx.x < E_) counts[threadIdx.x] = 0;
}

// ---------------- x -> bf16 ----------------
__global__ __launch_bounds__(256) void cvt_k(const float* __restrict__ x, unsigned short* __restrict__ xb) {
  size_t i = ((size_t)blockIdx.x * 256 + threadIdx.x) * 8;
  float4 a = *(const float4*)(x + i);
  float4 b = *(const float4*)(x + i + 4);
  u16x8 o;
  o[0]=bfb(a.x); o[1]=bfb(a.y); o[2]=bfb(a.z); o[3]=bfb(a.w);
  o[4]=bfb(b.x); o[5]=bfb(b.y); o[6]=bfb(b.z); o[7]=bfb(b.w);
  *(u16x8*)(xb + i) = o;
}

// ---------------- transpose+convert: src fp32 [K,N] -> dst bf16 [N,K] ----------------
__global__ __launch_bounds__(256) void tconv_k(const float* __restrict__ src, bf16* __restrict__ dst,
                                               int K, int N) {
  __shared__ bf16 lt[64][66];
  const int t = threadIdx.x;
  const size_t boff = (size_t)blockIdx.z * K * N;
  const int k0 = blockIdx.x * 64, n0 = blockIdx.y * 64;
  const float* s = src + boff;
  bf16* d = dst + boff;
  #pragma unroll
  for (int p = 0; p < 4; ++p) {
    int r = p * 16 + (t >> 4);
    int c = (t & 15) * 4;
    float4 v = *(const float4*)(s + (size_t)(k0 + r) * N + n0 + c);
    lt[c+0][r] = (bf16)v.x; lt[c+1][r] = (bf16)v.y;
    lt[c+2][r] = (bf16)v.z; lt[c+3][r] = (bf16)v.w;
  }
  __syncthreads();
  #pragma unroll
  for (int q = 0; q < 2; ++q) {
    int n  = q * 32 + (t >> 3);
    int ks = (t & 7) * 8;
    bf16x8 o;
    #pragma unroll
    for (int j = 0; j < 8; ++j) o[j] = lt[n][ks + j];
    *(bf16x8*)(d + (size_t)(n0 + n) * K + k0 + ks) = o;
  }
}

// ---------------- router: logits (fp32), top-4, softmax, expert lists ----------------
__global__ __launch_bounds__(64) void router_k(const float* __restrict__ x, const float* __restrict__ gw,
                                               float* __restrict__ logits, int* __restrict__ counts,
                                               int* __restrict__ tlist, float* __restrict__ wlist) {
  int t = blockIdx.x;
  int l = threadIdx.x;
  int e = l & 31;
  int half = l >> 5;
  const float* xr = x + (size_t)t * H_ + half * (H_/2);
  const float* g  = gw + (size_t)(half * (H_/2)) * E_ + e;
  float a0=0.f, a1=0.f, a2=0.f, a3=0.f;
  for (int h = 0; h < H_/2; h += 4) {
    a0 = fmaf(xr[h],   g[(size_t)h*E_],     a0);
    a1 = fmaf(xr[h+1], g[(size_t)(h+1)*E_], a1);
    a2 = fmaf(xr[h+2], g[(size_t)(h+2)*E_], a2);
    a3 = fmaf(xr[h+3], g[(size_t)(h+3)*E_], a3);
  }
  float acc = (a0+a1)+(a2+a3);
  acc += __shfl_xor(acc, 32);
  if (l < E_) logits[(size_t)t*E_ + l] = acc;

  float cur = (l < E_) ? acc : -INFINITY;
  int myidx = (l < E_) ? e : 1000;
  float tv0,tv1,tv2,tv3; int ti0,ti1,ti2,ti3;
  { float v=cur; int vi=myidx; wave_argmax(v,vi); tv0=v; ti0=vi; if (myidx==vi) cur=-INFINITY; }
  { float v=cur; int vi=myidx; wave_argmax(v,vi); tv1=v; ti1=vi; if (myidx==vi) cur=-INFINITY; }
  { float v=cur; int vi=myidx; wave_argmax(v,vi); tv2=v; ti2=vi; if (myidx==vi) cur=-INFINITY; }
  { float v=cur; int vi=myidx; wave_argmax(v,vi); tv3=v; ti3=vi; }
  float w0 = 1.f;
  float w1 = __expf(tv1 - tv0);
  float w2 = __expf(tv2 - tv0);
  float w3 = __expf(tv3 - tv0);
  float inv = 1.f / (w0+w1+w2+w3);
  if (l < KSEL) {
    float myw = ((l==0)?w0:(l==1)?w1:(l==2)?w2:w3) * inv;
    int   myi = ((l==0)?ti0:(l==1)?ti1:(l==2)?ti2:ti3);
    int pos = atomicAdd(&counts[myi], 1);
    tlist[myi*T_ + pos] = (t << 2) | l;
    wlist[myi*T_ + pos] = myw;
  }
}

// ---------------- tiled MFMA GEMM (BK=32, replay-verified structure) ----------------
// MODE 0: y1 = silu(xb @ ws1)              -> bf16 Cb
// MODE 1: out += y1 @ ws2 (split-K atomic) -> f32 Cf
// MODE 2: act[entry] = silu(gather(xb) @ w1[e]) * w   -> bf16
// MODE 3: out[t] += gather(act) @ w2[e]   (atomic)    -> f32
// Dense modes: 1-D x-grid with XCD-chunked bijective swizzle (nwg % 8 == 0)
// so each XCD gets a contiguous logical range -> B-panel reuse in its L2.
// Routed modes: blockIdx.x = e*NT + nt (all live), blockIdx.y = mt.
template<int MODE, int KDIM, int NDIM, int ASTR, int KSPLIT>
__global__ __launch_bounds__(256) void gemm_k(
    const bf16* __restrict__ A, const bf16* __restrict__ Bt,
    bf16* __restrict__ Cb, float* __restrict__ Cf,
    const int* __restrict__ tlist, const float* __restrict__ wlist,
    const int* __restrict__ counts)
{
  __shared__ __align__(16) char smem[16384];
  char* As = smem;            // 128 rows x 32 k bf16 (64B rows, slot-swizzled)
  char* Bs = smem + 8192;     // 128 cols x 32 k bf16 (64B rows, slot-swizzled)
  const int tid = threadIdx.x;

  int mt, nt, e = 0, kz = 0;
  int nrows = T_;
  const int* lst = nullptr;
  const bf16* Btp = Bt;
  if constexpr (MODE == 2 || MODE == 3) {
    constexpr int NT = NDIM / 128;
    e  = blockIdx.x / NT;
    nt = blockIdx.x % NT;
    mt = blockIdx.y;
    nrows = counts[e];
    if (mt * 128 >= nrows) return;
    lst = tlist + e*T_;
    Btp = Bt + (size_t)e * ((size_t)KDIM * NDIM);
  } else {
    // XCD-chunked bijective swizzle; nwg = 16 * (NDIM/128) blocks in x
    constexpr int NWG = 16 * (NDIM / 128);
    constexpr int CPX = NWG / 8;
    int id = blockIdx.x;
    int lg = (id & 7) * CPX + (id >> 3);
    mt = lg & 15;
    nt = lg >> 4;
    if constexpr (KSPLIT > 1) kz = blockIdx.z;
  }
  const int mrow0 = mt*128, ncol0 = nt*128;

  // A staging bases; source pre-swizzled so linear global_load_lds dest + swizzled read agree
  const bf16* abase[2];
  int aoffs[2];
  #pragma unroll
  for (int hh = 0; hh < 2; ++hh) {
    int lidx = hh*256 + tid;
    int row  = lidx >> 2;
    int slog = (lidx & 3) ^ (row & 3);
    aoffs[hh] = slog * 8;
    int ri = mrow0 + row;
    if constexpr (MODE == 2) {
      int tt = (ri < nrows) ? (lst[ri] >> 2) : 0;
      abase[hh] = A + (size_t)tt * ASTR;
    } else if constexpr (MODE == 3) {
      int ar = (ri < nrows) ? lst[ri] : 0;
      abase[hh] = A + (size_t)ar * ASTR;
    } else {
      abase[hh] = A + (size_t)ri * ASTR;
    }
  }

  // B staging: same pattern, from bf16 [N,K]
  const bf16* bbase2[2];
  int boffs[2];
  #pragma unroll
  for (int hh = 0; hh < 2; ++hh) {
    int lidx = hh*256 + tid;
    int row  = lidx >> 2;
    int slog = (lidx & 3) ^ (row & 3);
    boffs[hh] = slog * 8;
    bbase2[hh] = Btp + (size_t)(ncol0 + row) * KDIM;
  }

  const int l  = tid & 63;
  const int wv = tid >> 6;
  const int wr = wv >> 1, wc = wv & 1;
  const int ss = l >> 4;

  f32x4 acc[4][4] = {};

  constexpr int ITERS = KDIM / 32 / KSPLIT;
  const int kt0 = kz * ITERS;

  for (int kt = kt0; kt < kt0 + ITERS; ++kt) {
    const int k0 = kt * 32;
    __syncthreads();
    #pragma unroll
    for (int hh = 0; hh < 2; ++hh)
      gload_lds16(abase[hh] + k0 + aoffs[hh], As + (hh*256 + tid)*16);
    #pragma unroll
    for (int hh = 0; hh < 2; ++hh)
      gload_lds16(bbase2[hh] + k0 + boffs[hh], Bs + (hh*256 + tid)*16);
    __syncthreads();
    bf16x8 af[4], bfr[4];
    #pragma unroll
    for (int mf = 0; mf < 4; ++mf) {
      int r = wr*64 + mf*16 + (l & 15);
      af[mf] = *(const bf16x8*)(As + r*64 + ((ss ^ (r & 3)) << 4));
    }
    #pragma unroll
    for (int nf = 0; nf < 4; ++nf) {
      int c = wc*64 + nf*16 + (l & 15);
      bfr[nf] = *(const bf16x8*)(Bs + c*64 + ((ss ^ (c & 3)) << 4));
    }
    #pragma unroll
    for (int mf = 0; mf < 4; ++mf)
      #pragma unroll
      for (int nf = 0; nf < 4; ++nf)
        acc[mf][nf] = __builtin_amdgcn_mfma_f32_16x16x32_bf16(af[mf], bfr[nf], acc[mf][nf], 0, 0, 0);
  }

  // epilogue — C/D layout: row=(l>>4)*4+j, col=l&15 within each 16x16 frag
  #pragma unroll
  for (int mf = 0; mf < 4; ++mf) {
    #pragma unroll
    for (int j = 0; j < 4; ++j) {
      const int rloc = wr*64 + mf*16 + (l >> 4)*4 + j;
      const int grow = mrow0 + rloc;
      if constexpr (MODE == 0) {
        #pragma unroll
        for (int nf = 0; nf < 4; ++nf) {
          int col = ncol0 + wc*64 + nf*16 + (l & 15);
          Cb[(size_t)grow * NDIM + col] = (bf16)silu_f(acc[mf][nf][j]);
        }
      } else if constexpr (MODE == 1) {
        #pragma unroll
        for (int nf = 0; nf < 4; ++nf) {
          int col = ncol0 + wc*64 + nf*16 + (l & 15);
          atomicAdd(Cf + (size_t)grow * NDIM + col, acc[mf][nf][j]);
        }
      } else if constexpr (MODE == 2) {
        if (grow < nrows) {
          int entry = lst[grow];
          float wg = wlist[e*T_ + grow];
          #pragma unroll
          for (int nf = 0; nf < 4; ++nf) {
            int col = ncol0 + wc*64 + nf*16 + (l & 15);
            Cb[(size_t)entry * NDIM + col] = (bf16)(silu_f(acc[mf][nf][j]) * wg);
          }
        }
      } else {
        if (grow < nrows) {
          int entry = lst[grow];
          int tt = entry >> 2;
          #pragma unroll
          for (int nf = 0; nf < 4; ++nf) {
            int col = ncol0 + wc*64 + nf*16 + (l & 15);
            atomicAdd(Cf + (size_t)tt * H_ + col, acc[mf][nf][j]);
          }
        }
      }
    }
  }
}

extern "C" void kernel_launch(void* const* d_in, const int* in_sizes, int n_in,
                              void* d_out, int out_size, void* d_ws, size_t ws_size,
                              hipStream_t stream) {
  const float* x   = (const float*)d_in[0];
  const float* gw  = (const float*)d_in[1];
  const float* w1  = (const float*)d_in[2];
  const float* w2  = (const float*)d_in[3];
  const float* ws1 = (const float*)d_in[4];
  const float* ws2 = (const float*)d_in[5];
  float* out    = (float*)d_out;
  float* logits = out + (size_t)T_ * H_;

  char* ws = (char*)d_ws;
  const size_t off_xb   = 0;
  const size_t off_y1   = off_xb  + (size_t)T_ * H_ * 2;
  const size_t off_act  = off_y1  + (size_t)T_ * I_ * 2;
  const size_t off_cnt  = off_act + (size_t)T_ * 4 * M_ * 2;
  const size_t off_tl   = off_cnt + 256;
  const size_t off_wl   = off_tl  + (size_t)E_ * T_ * 4;
  const size_t off_ws1t = off_wl  + (size_t)E_ * T_ * 4;
  const size_t off_ws2t = off_ws1t + (size_t)I_ * H_ * 2;
  const size_t off_w1t  = off_ws2t + (size_t)H_ * I_ * 2;
  const size_t off_w2t  = off_w1t + (size_t)E_ * M_ * H_ * 2;

  const bf16* xb = (const bf16*)(ws + off_xb);
  bf16* y1  = (bf16*)(ws + off_y1);
  bf16* act = (bf16*)(ws + off_act);
  int*  counts = (int*)(ws + off_cnt);
  int*  tlist  = (int*)(ws + off_tl);
  float* wlist = (float*)(ws + off_wl);
  bf16* ws1t = (bf16*)(ws + off_ws1t);
  bf16* ws2t = (bf16*)(ws + off_ws2t);
  bf16* w1t  = (bf16*)(ws + off_w1t);
  bf16* w2t  = (bf16*)(ws + off_w2t);

  prep_k<<<4096, 256, 0, stream>>>(out, counts);
  router_k<<<T_, 64, 0, stream>>>(x, gw, logits, counts, tlist, wlist);
  cvt_k<<<2048, 256, 0, stream>>>(x, (unsigned short*)(ws + off_xb));

  tconv_k<<<dim3(H_/64, I_/64, 1),  256, 0, stream>>>(ws1, ws1t, H_, I_);
  tconv_k<<<dim3(I_/64, H_/64, 1),  256, 0, stream>>>(ws2, ws2t, I_, H_);
  tconv_k<<<dim3(H_/64, M_/64, E_), 256, 0, stream>>>(w1, w1t, H_, M_);
  tconv_k<<<dim3(M_/64, H_/64, E_), 256, 0, stream>>>(w2, w2t, M_, H_);

  gemm_k<0, 2048, 8192, 2048, 1><<<dim3(1024), 256, 0, stream>>>(
      xb, ws1t, y1, nullptr, nullptr, nullptr, nullptr);
  gemm_k<1, 8192, 2048, 8192, 4><<<dim3(256, 1, 4), 256, 0, stream>>>(
      y1, ws2t, nullptr, out, nullptr, nullptr, nullptr);
  gemm_k<2, 2048, 1408, 2048, 1><<<dim3(11*E_, 16), 256, 0, stream>>>(
      xb, w1t, act, nullptr, tlist, wlist, counts);
  gemm_k<3, 1408, 2048, 1408, 1><<<dim3(16*E_, 16), 256, 0, stream>>>(
      act, w2t, nullptr, out, tlist, nullptr, counts);
}

// Round 6
// 857.325 us; speedup vs baseline: 1.0463x; 1.0463x over previous
//
#include <hip/hip_runtime.h>

#define H_ 2048
#define E_ 32
#define KSEL 4
#define M_ 1408
#define I_ 8192
#define T_ 2048

typedef __bf16 bf16;
typedef bf16 bf16x8 __attribute__((ext_vector_type(8)));
typedef float f32x4 __attribute__((ext_vector_type(4)));
typedef unsigned short u16x8 __attribute__((ext_vector_type(8)));
typedef unsigned int u32x4 __attribute__((ext_vector_type(4)));

static __device__ __forceinline__ unsigned short bfb(float f) {
  return __builtin_bit_cast(unsigned short, (bf16)f);
}

static __device__ __forceinline__ void gload_lds16(const void* g, void* l) {
  __builtin_amdgcn_global_load_lds((const __attribute__((address_space(1))) void*)g,
                                   (__attribute__((address_space(3))) void*)l, 16, 0, 0);
}

static __device__ __forceinline__ float silu_f(float v) {
  return v / (1.f + __expf(-v));
}

static __device__ __forceinline__ void wave_argmax(float& v, int& vi) {
  #pragma unroll
  for (int off = 32; off >= 1; off >>= 1) {
    float ov = __shfl_xor(v, off);
    int   oi = __shfl_xor(vi, off);
    if (ov > v || (ov == v && oi < vi)) { v = ov; vi = oi; }
  }
}

// ---------------- prep: zero out[T,H] and counts ----------------
__global__ __launch_bounds__(256) void prep_k(float* __restrict__ out, int* __restrict__ counts) {
  size_t i = ((size_t)blockIdx.x * 256 + threadIdx.x) * 4;
  *(float4*)(out + i) = make_float4(0.f, 0.f, 0.f, 0.f);
  if (blockIdx.x == 0 && threadIdx.x < E_) counts[threadIdx.x] = 0;
}

// ---------------- x -> bf16 ----------------
__global__ __launch_bounds__(256) void cvt_k(const float* __restrict__ x, unsigned short* __restrict__ xb) {
  size_t i = ((size_t)blockIdx.x * 256 + threadIdx.x) * 8;
  float4 a = *(const float4*)(x + i);
  float4 b = *(const float4*)(x + i + 4);
  u16x8 o;
  o[0]=bfb(a.x); o[1]=bfb(a.y); o[2]=bfb(a.z); o[3]=bfb(a.w);
  o[4]=bfb(b.x); o[5]=bfb(b.y); o[6]=bfb(b.z); o[7]=bfb(b.w);
  *(u16x8*)(xb + i) = o;
}

// ---------------- router: logits (fp32), top-4, softmax, expert lists ----------------
__global__ __launch_bounds__(64) void router_k(const float* __restrict__ x, const float* __restrict__ gw,
                                               float* __restrict__ logits, int* __restrict__ counts,
                                               int* __restrict__ tlist, float* __restrict__ wlist) {
  int t = blockIdx.x;
  int l = threadIdx.x;
  int e = l & 31;
  int half = l >> 5;
  const float* xr = x + (size_t)t * H_ + half * (H_/2);
  const float* g  = gw + (size_t)(half * (H_/2)) * E_ + e;
  float a0=0.f, a1=0.f, a2=0.f, a3=0.f;
  for (int h = 0; h < H_/2; h += 4) {
    a0 = fmaf(xr[h],   g[(size_t)h*E_],     a0);
    a1 = fmaf(xr[h+1], g[(size_t)(h+1)*E_], a1);
    a2 = fmaf(xr[h+2], g[(size_t)(h+2)*E_], a2);
    a3 = fmaf(xr[h+3], g[(size_t)(h+3)*E_], a3);
  }
  float acc = (a0+a1)+(a2+a3);
  acc += __shfl_xor(acc, 32);
  if (l < E_) logits[(size_t)t*E_ + l] = acc;

  float cur = (l < E_) ? acc : -INFINITY;
  int myidx = (l < E_) ? e : 1000;
  float tv0,tv1,tv2,tv3; int ti0,ti1,ti2,ti3;
  { float v=cur; int vi=myidx; wave_argmax(v,vi); tv0=v; ti0=vi; if (myidx==vi) cur=-INFINITY; }
  { float v=cur; int vi=myidx; wave_argmax(v,vi); tv1=v; ti1=vi; if (myidx==vi) cur=-INFINITY; }
  { float v=cur; int vi=myidx; wave_argmax(v,vi); tv2=v; ti2=vi; if (myidx==vi) cur=-INFINITY; }
  { float v=cur; int vi=myidx; wave_argmax(v,vi); tv3=v; ti3=vi; }
  float w0 = 1.f;
  float w1 = __expf(tv1 - tv0);
  float w2 = __expf(tv2 - tv0);
  float w3 = __expf(tv3 - tv0);
  float inv = 1.f / (w0+w1+w2+w3);
  if (l < KSEL) {
    float myw = ((l==0)?w0:(l==1)?w1:(l==2)?w2:w3) * inv;
    int   myi = ((l==0)?ti0:(l==1)?ti1:(l==2)?ti2:ti3);
    int pos = atomicAdd(&counts[myi], 1);
    tlist[myi*T_ + pos] = (t << 2) | l;
    wlist[myi*T_ + pos] = myw;
  }
}

// ---------------- tiled MFMA GEMM (BK=32, replay-verified sync structure) ----------------
// B is consumed DIRECTLY from fp32 [K,N]: coalesced reg-load (lane=consecutive n,
// 16 k-rows/thread), cvt to bf16, pack, ds_write_b128 into slot-major LDS
// [slot(4)][n(128)][16B] — conflict-free on write (consecutive lanes ->
// consecutive 16B) and read (2-way = free). No tconv pass, no transposed copies.
// A staged via global_load_lds (source pre-swizzled, linear dest — rule 21).
// MODE 0: y1 = silu(xb @ ws1)              -> bf16 Cb
// MODE 1: out += y1 @ ws2 (split-K atomic) -> f32 Cf
// MODE 2: act[entry] = silu(gather(xb) @ w1[e]) * w   -> bf16
// MODE 3: out[t] += gather(act) @ w2[e]   (atomic)    -> f32
// Dense modes: 1-D x-grid, XCD-chunked bijective swizzle (nwg % 8 == 0).
// Routed modes: blockIdx.x = e*NT + nt (all live), blockIdx.y = mt.
template<int MODE, int KDIM, int NDIM, int ASTR, int KSPLIT>
__global__ __launch_bounds__(256) void gemm_k(
    const bf16* __restrict__ A, const float* __restrict__ Bf,
    bf16* __restrict__ Cb, float* __restrict__ Cf,
    const int* __restrict__ tlist, const float* __restrict__ wlist,
    const int* __restrict__ counts)
{
  __shared__ __align__(16) char smem[16384];
  char* As = smem;            // 128 rows x 32 k bf16 (64B rows, slot-swizzled)
  char* Bs = smem + 8192;     // slot-major [4][128][16B]
  const int tid = threadIdx.x;

  int mt, nt, e = 0, kz = 0;
  int nrows = T_;
  const int* lst = nullptr;
  const float* Bp = Bf;
  if constexpr (MODE == 2 || MODE == 3) {
    constexpr int NT = NDIM / 128;
    e  = blockIdx.x / NT;
    nt = blockIdx.x % NT;
    mt = blockIdx.y;
    nrows = counts[e];
    if (mt * 128 >= nrows) return;
    lst = tlist + e*T_;
    Bp = Bf + (size_t)e * ((size_t)KDIM * NDIM);
  } else {
    constexpr int NWG = 16 * (NDIM / 128);
    constexpr int CPX = NWG / 8;
    int id = blockIdx.x;
    int lg = (id & 7) * CPX + (id >> 3);
    mt = lg & 15;
    nt = lg >> 4;
    if constexpr (KSPLIT > 1) kz = blockIdx.z;
  }
  const int mrow0 = mt*128, ncol0 = nt*128;

  // A staging bases; source pre-swizzled so linear global_load_lds dest + swizzled read agree
  const bf16* abase[2];
  int aoffs[2];
  #pragma unroll
  for (int hh = 0; hh < 2; ++hh) {
    int lidx = hh*256 + tid;
    int row  = lidx >> 2;
    int slog = (lidx & 3) ^ (row & 3);
    aoffs[hh] = slog * 8;
    int ri = mrow0 + row;
    if constexpr (MODE == 2) {
      int tt = (ri < nrows) ? (lst[ri] >> 2) : 0;
      abase[hh] = A + (size_t)tt * ASTR;
    } else if constexpr (MODE == 3) {
      int ar = (ri < nrows) ? lst[ri] : 0;
      abase[hh] = A + (size_t)ar * ASTR;
    } else {
      abase[hh] = A + (size_t)ri * ASTR;
    }
  }

  // B staging: thread covers n = tid&127, k-half bh = tid>>7 (16 rows)
  const int bn = tid & 127;
  const int bh = tid >> 7;
  const float* bsrc0 = Bp + (size_t)(bh * 16) * NDIM + ncol0 + bn;
  char* bdst0 = Bs + (bh*2)*2048 + bn*16;

  const int l  = tid & 63;
  const int wv = tid >> 6;
  const int wr = wv >> 1, wc = wv & 1;
  const int ss = l >> 4;

  f32x4 acc[4][4] = {};

  constexpr int ITERS = KDIM / 32 / KSPLIT;
  const int kt0 = kz * ITERS;

  for (int kt = kt0; kt < kt0 + ITERS; ++kt) {
    const int k0 = kt * 32;
    __syncthreads();
    #pragma unroll
    for (int hh = 0; hh < 2; ++hh)
      gload_lds16(abase[hh] + k0 + aoffs[hh], As + (hh*256 + tid)*16);
    {
      const float* bs = bsrc0 + (size_t)k0 * NDIM;
      float bv[16];
      #pragma unroll
      for (int j = 0; j < 16; ++j) bv[j] = bs[(size_t)j * NDIM];
      unsigned pk[8];
      #pragma unroll
      for (int jj = 0; jj < 8; ++jj)
        pk[jj] = (unsigned)bfb(bv[2*jj]) | ((unsigned)bfb(bv[2*jj+1]) << 16);
      u32x4 lo, hi;
      lo[0]=pk[0]; lo[1]=pk[1]; lo[2]=pk[2]; lo[3]=pk[3];
      hi[0]=pk[4]; hi[1]=pk[5]; hi[2]=pk[6]; hi[3]=pk[7];
      *(u32x4*)(bdst0)        = lo;   // slot bh*2   : k = k0+bh*16 + 0..7
      *(u32x4*)(bdst0 + 2048) = hi;   // slot bh*2+1 : k = k0+bh*16 + 8..15
    }
    __syncthreads();
    bf16x8 af[4], bfr[4];
    #pragma unroll
    for (int mf = 0; mf < 4; ++mf) {
      int r = wr*64 + mf*16 + (l & 15);
      af[mf] = *(const bf16x8*)(As + r*64 + ((ss ^ (r & 3)) << 4));
    }
    #pragma unroll
    for (int nf = 0; nf < 4; ++nf) {
      int c = wc*64 + nf*16 + (l & 15);
      bfr[nf] = *(const bf16x8*)(Bs + ss*2048 + c*16);
    }
    #pragma unroll
    for (int mf = 0; mf < 4; ++mf)
      #pragma unroll
      for (int nf = 0; nf < 4; ++nf)
        acc[mf][nf] = __builtin_amdgcn_mfma_f32_16x16x32_bf16(af[mf], bfr[nf], acc[mf][nf], 0, 0, 0);
  }

  // epilogue — C/D layout: row=(l>>4)*4+j, col=l&15 within each 16x16 frag
  #pragma unroll
  for (int mf = 0; mf < 4; ++mf) {
    #pragma unroll
    for (int j = 0; j < 4; ++j) {
      const int rloc = wr*64 + mf*16 + (l >> 4)*4 + j;
      const int grow = mrow0 + rloc;
      if constexpr (MODE == 0) {
        #pragma unroll
        for (int nf = 0; nf < 4; ++nf) {
          int col = ncol0 + wc*64 + nf*16 + (l & 15);
          Cb[(size_t)grow * NDIM + col] = (bf16)silu_f(acc[mf][nf][j]);
        }
      } else if constexpr (MODE == 1) {
        #pragma unroll
        for (int nf = 0; nf < 4; ++nf) {
          int col = ncol0 + wc*64 + nf*16 + (l & 15);
          atomicAdd(Cf + (size_t)grow * NDIM + col, acc[mf][nf][j]);
        }
      } else if constexpr (MODE == 2) {
        if (grow < nrows) {
          int entry = lst[grow];
          float wg = wlist[e*T_ + grow];
          #pragma unroll
          for (int nf = 0; nf < 4; ++nf) {
            int col = ncol0 + wc*64 + nf*16 + (l & 15);
            Cb[(size_t)entry * NDIM + col] = (bf16)(silu_f(acc[mf][nf][j]) * wg);
          }
        }
      } else {
        if (grow < nrows) {
          int entry = lst[grow];
          int tt = entry >> 2;
          #pragma unroll
          for (int nf = 0; nf < 4; ++nf) {
            int col = ncol0 + wc*64 + nf*16 + (l & 15);
            atomicAdd(Cf + (size_t)tt * H_ + col, acc[mf][nf][j]);
          }
        }
      }
    }
  }
}

extern "C" void kernel_launch(void* const* d_in, const int* in_sizes, int n_in,
                              void* d_out, int out_size, void* d_ws, size_t ws_size,
                              hipStream_t stream) {
  const float* x   = (const float*)d_in[0];
  const float* gw  = (const float*)d_in[1];
  const float* w1  = (const float*)d_in[2];
  const float* w2  = (const float*)d_in[3];
  const float* ws1 = (const float*)d_in[4];
  const float* ws2 = (const float*)d_in[5];
  float* out    = (float*)d_out;
  float* logits = out + (size_t)T_ * H_;

  char* ws = (char*)d_ws;
  const size_t off_xb   = 0;
  const size_t off_y1   = off_xb  + (size_t)T_ * H_ * 2;
  const size_t off_act  = off_y1  + (size_t)T_ * I_ * 2;
  const size_t off_cnt  = off_act + (size_t)T_ * 4 * M_ * 2;
  const size_t off_tl   = off_cnt + 256;
  const size_t off_wl   = off_tl  + (size_t)E_ * T_ * 4;

  const bf16* xb = (const bf16*)(ws + off_xb);
  bf16* y1  = (bf16*)(ws + off_y1);
  bf16* act = (bf16*)(ws + off_act);
  int*  counts = (int*)(ws + off_cnt);
  int*  tlist  = (int*)(ws + off_tl);
  float* wlist = (float*)(ws + off_wl);

  prep_k<<<4096, 256, 0, stream>>>(out, counts);
  router_k<<<T_, 64, 0, stream>>>(x, gw, logits, counts, tlist, wlist);
  cvt_k<<<2048, 256, 0, stream>>>(x, (unsigned short*)(ws + off_xb));

  gemm_k<0, 2048, 8192, 2048, 1><<<dim3(1024), 256, 0, stream>>>(
      xb, ws1, y1, nullptr, nullptr, nullptr, nullptr);
  gemm_k<1, 8192, 2048, 8192, 4><<<dim3(256, 1, 4), 256, 0, stream>>>(
      y1, ws2, nullptr, out, nullptr, nullptr, nullptr);
  gemm_k<2, 2048, 1408, 2048, 1><<<dim3(11*E_, 16), 256, 0, stream>>>(
      xb, w1, act, nullptr, tlist, wlist, counts);
  gemm_k<3, 1408, 2048, 1408, 1><<<dim3(16*E_, 16), 256, 0, stream>>>(
      act, w2, nullptr, out, tlist, nullptr, counts);
}

// Round 7
// 854.027 us; speedup vs baseline: 1.0504x; 1.0039x over previous
//
#include <hip/hip_runtime.h>

#define H_ 2048
#define E_ 32
#define KSEL 4
#define M_ 1408
#define I_ 8192
#define T_ 2048

typedef __bf16 bf16;
typedef bf16 bf16x8 __attribute__((ext_vector_type(8)));
typedef float f32x4 __attribute__((ext_vector_type(4)));
typedef unsigned short u16x8 __attribute__((ext_vector_type(8)));
typedef unsigned int u32x4 __attribute__((ext_vector_type(4)));

static __device__ __forceinline__ unsigned short bfb(float f) {
  return __builtin_bit_cast(unsigned short, (bf16)f);
}

static __device__ __forceinline__ void gload_lds16(const void* g, void* l) {
  __builtin_amdgcn_global_load_lds((const __attribute__((address_space(1))) void*)g,
                                   (__attribute__((address_space(3))) void*)l, 16, 0, 0);
}

static __device__ __forceinline__ float silu_f(float v) {
  return v / (1.f + __expf(-v));
}

static __device__ __forceinline__ void wave_argmax(float& v, int& vi) {
  #pragma unroll
  for (int off = 32; off >= 1; off >>= 1) {
    float ov = __shfl_xor(v, off);
    int   oi = __shfl_xor(vi, off);
    if (ov > v || (ov == v && oi < vi)) { v = ov; vi = oi; }
  }
}

// ---------------- prep: zero out[T,H] and counts ----------------
__global__ __launch_bounds__(256) void prep_k(float* __restrict__ out, int* __restrict__ counts) {
  size_t i = ((size_t)blockIdx.x * 256 + threadIdx.x) * 4;
  *(float4*)(out + i) = make_float4(0.f, 0.f, 0.f, 0.f);
  if (blockIdx.x == 0 && threadIdx.x < E_) counts[threadIdx.x] = 0;
}

// ---------------- x -> bf16 ----------------
__global__ __launch_bounds__(256) void cvt_k(const float* __restrict__ x, unsigned short* __restrict__ xb) {
  size_t i = ((size_t)blockIdx.x * 256 + threadIdx.x) * 8;
  float4 a = *(const float4*)(x + i);
  float4 b = *(const float4*)(x + i + 4);
  u16x8 o;
  o[0]=bfb(a.x); o[1]=bfb(a.y); o[2]=bfb(a.z); o[3]=bfb(a.w);
  o[4]=bfb(b.x); o[5]=bfb(b.y); o[6]=bfb(b.z); o[7]=bfb(b.w);
  *(u16x8*)(xb + i) = o;
}

// ---------------- router: logits (fp32), top-4, softmax, expert lists ----------------
__global__ __launch_bounds__(64) void router_k(const float* __restrict__ x, const float* __restrict__ gw,
                                               float* __restrict__ logits, int* __restrict__ counts,
                                               int* __restrict__ tlist, float* __restrict__ wlist) {
  int t = blockIdx.x;
  int l = threadIdx.x;
  int e = l & 31;
  int half = l >> 5;
  const float* xr = x + (size_t)t * H_ + half * (H_/2);
  const float* g  = gw + (size_t)(half * (H_/2)) * E_ + e;
  float a0=0.f, a1=0.f, a2=0.f, a3=0.f;
  for (int h = 0; h < H_/2; h += 4) {
    a0 = fmaf(xr[h],   g[(size_t)h*E_],     a0);
    a1 = fmaf(xr[h+1], g[(size_t)(h+1)*E_], a1);
    a2 = fmaf(xr[h+2], g[(size_t)(h+2)*E_], a2);
    a3 = fmaf(xr[h+3], g[(size_t)(h+3)*E_], a3);
  }
  float acc = (a0+a1)+(a2+a3);
  acc += __shfl_xor(acc, 32);
  if (l < E_) logits[(size_t)t*E_ + l] = acc;

  float cur = (l < E_) ? acc : -INFINITY;
  int myidx = (l < E_) ? e : 1000;
  float tv0,tv1,tv2,tv3; int ti0,ti1,ti2,ti3;
  { float v=cur; int vi=myidx; wave_argmax(v,vi); tv0=v; ti0=vi; if (myidx==vi) cur=-INFINITY; }
  { float v=cur; int vi=myidx; wave_argmax(v,vi); tv1=v; ti1=vi; if (myidx==vi) cur=-INFINITY; }
  { float v=cur; int vi=myidx; wave_argmax(v,vi); tv2=v; ti2=vi; if (myidx==vi) cur=-INFINITY; }
  { float v=cur; int vi=myidx; wave_argmax(v,vi); tv3=v; ti3=vi; }
  float w0 = 1.f;
  float w1 = __expf(tv1 - tv0);
  float w2 = __expf(tv2 - tv0);
  float w3 = __expf(tv3 - tv0);
  float inv = 1.f / (w0+w1+w2+w3);
  if (l < KSEL) {
    float myw = ((l==0)?w0:(l==1)?w1:(l==2)?w2:w3) * inv;
    int   myi = ((l==0)?ti0:(l==1)?ti1:(l==2)?ti2:ti3);
    int pos = atomicAdd(&counts[myi], 1);
    tlist[myi*T_ + pos] = (t << 2) | l;
    wlist[myi*T_ + pos] = myw;
  }
}

// ---------------- tiled MFMA GEMM (BK=32, replay-verified sync structure) ----------------
// B consumed directly from fp32 [K,N] with T14 async-STAGE split: the 16
// per-thread B loads for step kt+1 are ISSUED right after barrier-2 of step kt
// (they fly during the MFMA phase) and consumed (cvt+pack+ds_write) after the
// next barrier-1. Both barriers intact — same sync skeleton as r5/r6 (verified).
// MODE 0: y1 = silu(xb @ ws1)              -> bf16 Cb
// MODE 1: out += y1 @ ws2 (split-K atomic) -> f32 Cf
// MODE 2: act[entry] = silu(gather(xb) @ w1[e]) * w   -> bf16
// MODE 3: out[t] += gather(act) @ w2[e]  (split-K atomic) -> f32
// Dense modes: 1-D x-grid, XCD-chunked bijective swizzle (nwg % 8 == 0).
// Routed modes: blockIdx.x = e*NT + nt (all live), blockIdx.y = mt, z = kz.
template<int MODE, int KDIM, int NDIM, int ASTR, int KSPLIT>
__global__ __launch_bounds__(256) void gemm_k(
    const bf16* __restrict__ A, const float* __restrict__ Bf,
    bf16* __restrict__ Cb, float* __restrict__ Cf,
    const int* __restrict__ tlist, const float* __restrict__ wlist,
    const int* __restrict__ counts)
{
  __shared__ __align__(16) char smem[16384];
  char* As = smem;            // 128 rows x 32 k bf16 (64B rows, slot-swizzled)
  char* Bs = smem + 8192;     // slot-major [4][128][16B]
  const int tid = threadIdx.x;

  int mt, nt, e = 0, kz = 0;
  int nrows = T_;
  const int* lst = nullptr;
  const float* Bp = Bf;
  if constexpr (MODE == 2 || MODE == 3) {
    constexpr int NT = NDIM / 128;
    e  = blockIdx.x / NT;
    nt = blockIdx.x % NT;
    mt = blockIdx.y;
    nrows = counts[e];
    if (mt * 128 >= nrows) return;
    lst = tlist + e*T_;
    Bp = Bf + (size_t)e * ((size_t)KDIM * NDIM);
    if constexpr (KSPLIT > 1) kz = blockIdx.z;
  } else {
    constexpr int NWG = 16 * (NDIM / 128);
    constexpr int CPX = NWG / 8;
    int id = blockIdx.x;
    int lg = (id & 7) * CPX + (id >> 3);
    mt = lg & 15;
    nt = lg >> 4;
    if constexpr (KSPLIT > 1) kz = blockIdx.z;
  }
  const int mrow0 = mt*128, ncol0 = nt*128;

  // A staging bases; source pre-swizzled so linear global_load_lds dest + swizzled read agree
  const bf16* abase[2];
  int aoffs[2];
  #pragma unroll
  for (int hh = 0; hh < 2; ++hh) {
    int lidx = hh*256 + tid;
    int row  = lidx >> 2;
    int slog = (lidx & 3) ^ (row & 3);
    aoffs[hh] = slog * 8;
    int ri = mrow0 + row;
    if constexpr (MODE == 2) {
      int tt = (ri < nrows) ? (lst[ri] >> 2) : 0;
      abase[hh] = A + (size_t)tt * ASTR;
    } else if constexpr (MODE == 3) {
      int ar = (ri < nrows) ? lst[ri] : 0;
      abase[hh] = A + (size_t)ar * ASTR;
    } else {
      abase[hh] = A + (size_t)ri * ASTR;
    }
  }

  // B staging: thread covers n = tid&127, k-half bh = tid>>7 (16 rows)
  const int bn = tid & 127;
  const int bh = tid >> 7;
  const float* bsrc0 = Bp + (size_t)(bh * 16) * NDIM + ncol0 + bn;
  char* bdst0 = Bs + (bh*2)*2048 + bn*16;

  const int l  = tid & 63;
  const int wv = tid >> 6;
  const int wr = wv >> 1, wc = wv & 1;
  const int ss = l >> 4;

  f32x4 acc[4][4] = {};

  constexpr int ITERS = KDIM / 32 / KSPLIT;   // 64, 64, 64, 22 — all even
  static_assert(ITERS % 2 == 0, "K-loop is 2-unrolled");
  const int kt0 = kz * ITERS;
  const int ktend = kt0 + ITERS;

  float vA0,vA1,vA2,vA3,vA4,vA5,vA6,vA7,vA8,vA9,vA10,vA11,vA12,vA13,vA14,vA15;
  float vB0,vB1,vB2,vB3,vB4,vB5,vB6,vB7,vB8,vB9,vB10,vB11,vB12,vB13,vB14,vB15;

#define LOADB(P, KT) do {                                            \
    const float* bs_ = bsrc0 + (size_t)((KT) * 32) * NDIM;           \
    P##0 = bs_[0];            P##1 = bs_[(size_t)1*NDIM];            \
    P##2 = bs_[(size_t)2*NDIM];  P##3 = bs_[(size_t)3*NDIM];         \
    P##4 = bs_[(size_t)4*NDIM];  P##5 = bs_[(size_t)5*NDIM];         \
    P##6 = bs_[(size_t)6*NDIM];  P##7 = bs_[(size_t)7*NDIM];         \
    P##8 = bs_[(size_t)8*NDIM];  P##9 = bs_[(size_t)9*NDIM];         \
    P##10 = bs_[(size_t)10*NDIM]; P##11 = bs_[(size_t)11*NDIM];      \
    P##12 = bs_[(size_t)12*NDIM]; P##13 = bs_[(size_t)13*NDIM];      \
    P##14 = bs_[(size_t)14*NDIM]; P##15 = bs_[(size_t)15*NDIM];      \
  } while (0)

#define WRITEB(P) do {                                               \
    u32x4 lo_, hi_;                                                  \
    lo_[0] = (unsigned)bfb(P##0)  | ((unsigned)bfb(P##1)  << 16);    \
    lo_[1] = (unsigned)bfb(P##2)  | ((unsigned)bfb(P##3)  << 16);    \
    lo_[2] = (unsigned)bfb(P##4)  | ((unsigned)bfb(P##5)  << 16);    \
    lo_[3] = (unsigned)bfb(P##6)  | ((unsigned)bfb(P##7)  << 16);    \
    hi_[0] = (unsigned)bfb(P##8)  | ((unsigned)bfb(P##9)  << 16);    \
    hi_[1] = (unsigned)bfb(P##10) | ((unsigned)bfb(P##11) << 16);    \
    hi_[2] = (unsigned)bfb(P##12) | ((unsigned)bfb(P##13) << 16);    \
    hi_[3] = (unsigned)bfb(P##14) | ((unsigned)bfb(P##15) << 16);    \
    *(u32x4*)(bdst0)        = lo_;                                   \
    *(u32x4*)(bdst0 + 2048) = hi_;                                   \
  } while (0)

#define MFMA_PHASE(KT) do {                                          \
    bf16x8 af[4], bfr[4];                                            \
    _Pragma("unroll")                                                \
    for (int mf = 0; mf < 4; ++mf) {                                 \
      int r = wr*64 + mf*16 + (l & 15);                              \
      af[mf] = *(const bf16x8*)(As + r*64 + ((ss ^ (r & 3)) << 4));  \
    }                                                                \
    _Pragma("unroll")                                                \
    for (int nf = 0; nf < 4; ++nf) {                                 \
      int c = wc*64 + nf*16 + (l & 15);                              \
      bfr[nf] = *(const bf16x8*)(Bs + ss*2048 + c*16);               \
    }                                                                \
    _Pragma("unroll")                                                \
    for (int mf = 0; mf < 4; ++mf)                                   \
      _Pragma("unroll")                                              \
      for (int nf = 0; nf < 4; ++nf)                                 \
        acc[mf][nf] = __builtin_amdgcn_mfma_f32_16x16x32_bf16(af[mf], bfr[nf], acc[mf][nf], 0, 0, 0); \
  } while (0)

#define ADMA(KT) do {                                                \
    _Pragma("unroll")                                                \
    for (int hh = 0; hh < 2; ++hh)                                   \
      gload_lds16(abase[hh] + (KT)*32 + aoffs[hh], As + (hh*256 + tid)*16); \
  } while (0)

  LOADB(vA, kt0);
  for (int kt = kt0; kt < ktend; kt += 2) {
    __syncthreads();
    ADMA(kt);
    WRITEB(vA);
    __syncthreads();
    LOADB(vB, kt + 1);           // flies during MFMA phase
    MFMA_PHASE(kt);

    __syncthreads();
    ADMA(kt + 1);
    WRITEB(vB);
    __syncthreads();
    if (kt + 2 < ktend) LOADB(vA, kt + 2);   // flies during MFMA phase
    MFMA_PHASE(kt + 1);
  }

#undef LOADB
#undef WRITEB
#undef MFMA_PHASE
#undef ADMA

  // epilogue — C/D layout: row=(l>>4)*4+j, col=l&15 within each 16x16 frag
  #pragma unroll
  for (int mf = 0; mf < 4; ++mf) {
    #pragma unroll
    for (int j = 0; j < 4; ++j) {
      const int rloc = wr*64 + mf*16 + (l >> 4)*4 + j;
      const int grow = mrow0 + rloc;
      if constexpr (MODE == 0) {
        #pragma unroll
        for (int nf = 0; nf < 4; ++nf) {
          int col = ncol0 + wc*64 + nf*16 + (l & 15);
          Cb[(size_t)grow * NDIM + col] = (bf16)silu_f(acc[mf][nf][j]);
        }
      } else if constexpr (MODE == 1) {
        #pragma unroll
        for (int nf = 0; nf < 4; ++nf) {
          int col = ncol0 + wc*64 + nf*16 + (l & 15);
          atomicAdd(Cf + (size_t)grow * NDIM + col, acc[mf][nf][j]);
        }
      } else if constexpr (MODE == 2) {
        if (grow < nrows) {
          int entry = lst[grow];
          float wg = wlist[e*T_ + grow];
          #pragma unroll
          for (int nf = 0; nf < 4; ++nf) {
            int col = ncol0 + wc*64 + nf*16 + (l & 15);
            Cb[(size_t)entry * NDIM + col] = (bf16)(silu_f(acc[mf][nf][j]) * wg);
          }
        }
      } else {
        if (grow < nrows) {
          int entry = lst[grow];
          int tt = entry >> 2;
          #pragma unroll
          for (int nf = 0; nf < 4; ++nf) {
            int col = ncol0 + wc*64 + nf*16 + (l & 15);
            atomicAdd(Cf + (size_t)tt * H_ + col, acc[mf][nf][j]);
          }
        }
      }
    }
  }
}

extern "C" void kernel_launch(void* const* d_in, const int* in_sizes, int n_in,
                              void* d_out, int out_size, void* d_ws, size_t ws_size,
                              hipStream_t stream) {
  const float* x   = (const float*)d_in[0];
  const float* gw  = (const float*)d_in[1];
  const float* w1  = (const float*)d_in[2];
  const float* w2  = (const float*)d_in[3];
  const float* ws1 = (const float*)d_in[4];
  const float* ws2 = (const float*)d_in[5];
  float* out    = (float*)d_out;
  float* logits = out + (size_t)T_ * H_;

  char* ws = (char*)d_ws;
  const size_t off_xb   = 0;
  const size_t off_y1   = off_xb  + (size_t)T_ * H_ * 2;
  const size_t off_act  = off_y1  + (size_t)T_ * I_ * 2;
  const size_t off_cnt  = off_act + (size_t)T_ * 4 * M_ * 2;
  const size_t off_tl   = off_cnt + 256;
  const size_t off_wl   = off_tl  + (size_t)E_ * T_ * 4;

  const bf16* xb = (const bf16*)(ws + off_xb);
  bf16* y1  = (bf16*)(ws + off_y1);
  bf16* act = (bf16*)(ws + off_act);
  int*  counts = (int*)(ws + off_cnt);
  int*  tlist  = (int*)(ws + off_tl);
  float* wlist = (float*)(ws + off_wl);

  prep_k<<<4096, 256, 0, stream>>>(out, counts);
  router_k<<<T_, 64, 0, stream>>>(x, gw, logits, counts, tlist, wlist);
  cvt_k<<<2048, 256, 0, stream>>>(x, (unsigned short*)(ws + off_xb));

  gemm_k<0, 2048, 8192, 2048, 1><<<dim3(1024), 256, 0, stream>>>(
      xb, ws1, y1, nullptr, nullptr, nullptr, nullptr);
  gemm_k<1, 8192, 2048, 8192, 4><<<dim3(256, 1, 4), 256, 0, stream>>>(
      y1, ws2, nullptr, out, nullptr, nullptr, nullptr);
  gemm_k<2, 2048, 1408, 2048, 1><<<dim3(11*E_, 16), 256, 0, stream>>>(
      xb, w1, act, nullptr, tlist, wlist, counts);
  gemm_k<3, 1408, 2048, 1408, 2><<<dim3(16*E_, 16, 2), 256, 0, stream>>>(
      act, w2, nullptr, out, tlist, nullptr, counts);
}

// Round 8
// 827.318 us; speedup vs baseline: 1.0843x; 1.0323x over previous
//
#include <hip/hip_runtime.h>

#define H_ 2048
#define E_ 32
#define KSEL 4
#define M_ 1408
#define I_ 8192
#define T_ 2048

typedef __bf16 bf16;
typedef bf16 bf16x8 __attribute__((ext_vector_type(8)));
typedef float f32x4 __attribute__((ext_vector_type(4)));
typedef unsigned short u16x8 __attribute__((ext_vector_type(8)));
typedef unsigned int u32x4 __attribute__((ext_vector_type(4)));

static __device__ __forceinline__ unsigned short bfb(float f) {
  return __builtin_bit_cast(unsigned short, (bf16)f);
}

static __device__ __forceinline__ void gload_lds16(const void* g, void* l) {
  __builtin_amdgcn_global_load_lds((const __attribute__((address_space(1))) void*)g,
                                   (__attribute__((address_space(3))) void*)l, 16, 0, 0);
}

static __device__ __forceinline__ float silu_f(float v) {
  return v / (1.f + __expf(-v));
}

static __device__ __forceinline__ void wave_argmax(float& v, int& vi) {
  #pragma unroll
  for (int off = 32; off >= 1; off >>= 1) {
    float ov = __shfl_xor(v, off);
    int   oi = __shfl_xor(vi, off);
    if (ov > v || (ov == v && oi < vi)) { v = ov; vi = oi; }
  }
}

// ---------------- prep: zero out[T,H] and counts ----------------
__global__ __launch_bounds__(256) void prep_k(float* __restrict__ out, int* __restrict__ counts) {
  size_t i = ((size_t)blockIdx.x * 256 + threadIdx.x) * 4;
  *(float4*)(out + i) = make_float4(0.f, 0.f, 0.f, 0.f);
  if (blockIdx.x == 0 && threadIdx.x < E_) counts[threadIdx.x] = 0;
}

// ---------------- x -> bf16 ----------------
__global__ __launch_bounds__(256) void cvt_k(const float* __restrict__ x, unsigned short* __restrict__ xb) {
  size_t i = ((size_t)blockIdx.x * 256 + threadIdx.x) * 8;
  float4 a = *(const float4*)(x + i);
  float4 b = *(const float4*)(x + i + 4);
  u16x8 o;
  o[0]=bfb(a.x); o[1]=bfb(a.y); o[2]=bfb(a.z); o[3]=bfb(a.w);
  o[4]=bfb(b.x); o[5]=bfb(b.y); o[6]=bfb(b.z); o[7]=bfb(b.w);
  *(u16x8*)(xb + i) = o;
}

// ---------------- combine: out[t][h] += sum_slot scratch[t*4+slot][h] ----------------
__global__ __launch_bounds__(256) void combine_k(const float* __restrict__ sc, float* __restrict__ out) {
  size_t i = ((size_t)blockIdx.x * 256 + threadIdx.x) * 4;
  int t = (int)(i >> 11);
  int h = (int)(i & 2047);
  const float* s = sc + (size_t)(t * 4) * H_ + h;
  float4 a = *(const float4*)(s);
  float4 b = *(const float4*)(s + H_);
  float4 c = *(const float4*)(s + 2 * H_);
  float4 d = *(const float4*)(s + 3 * H_);
  float4 o = *(const float4*)(out + i);
  o.x += a.x + b.x + c.x + d.x;
  o.y += a.y + b.y + c.y + d.y;
  o.z += a.z + b.z + c.z + d.z;
  o.w += a.w + b.w + c.w + d.w;
  *(float4*)(out + i) = o;
}

// ---------------- router: logits (fp32), top-4, softmax, expert lists ----------------
__global__ __launch_bounds__(64) void router_k(const float* __restrict__ x, const float* __restrict__ gw,
                                               float* __restrict__ logits, int* __restrict__ counts,
                                               int* __restrict__ tlist, float* __restrict__ wlist) {
  int t = blockIdx.x;
  int l = threadIdx.x;
  int e = l & 31;
  int half = l >> 5;
  const float* xr = x + (size_t)t * H_ + half * (H_/2);
  const float* g  = gw + (size_t)(half * (H_/2)) * E_ + e;
  float a0=0.f, a1=0.f, a2=0.f, a3=0.f;
  for (int h = 0; h < H_/2; h += 4) {
    a0 = fmaf(xr[h],   g[(size_t)h*E_],     a0);
    a1 = fmaf(xr[h+1], g[(size_t)(h+1)*E_], a1);
    a2 = fmaf(xr[h+2], g[(size_t)(h+2)*E_], a2);
    a3 = fmaf(xr[h+3], g[(size_t)(h+3)*E_], a3);
  }
  float acc = (a0+a1)+(a2+a3);
  acc += __shfl_xor(acc, 32);
  if (l < E_) logits[(size_t)t*E_ + l] = acc;

  float cur = (l < E_) ? acc : -INFINITY;
  int myidx = (l < E_) ? e : 1000;
  float tv0,tv1,tv2,tv3; int ti0,ti1,ti2,ti3;
  { float v=cur; int vi=myidx; wave_argmax(v,vi); tv0=v; ti0=vi; if (myidx==vi) cur=-INFINITY; }
  { float v=cur; int vi=myidx; wave_argmax(v,vi); tv1=v; ti1=vi; if (myidx==vi) cur=-INFINITY; }
  { float v=cur; int vi=myidx; wave_argmax(v,vi); tv2=v; ti2=vi; if (myidx==vi) cur=-INFINITY; }
  { float v=cur; int vi=myidx; wave_argmax(v,vi); tv3=v; ti3=vi; }
  float w0 = 1.f;
  float w1 = __expf(tv1 - tv0);
  float w2 = __expf(tv2 - tv0);
  float w3 = __expf(tv3 - tv0);
  float inv = 1.f / (w0+w1+w2+w3);
  if (l < KSEL) {
    float myw = ((l==0)?w0:(l==1)?w1:(l==2)?w2:w3) * inv;
    int   myi = ((l==0)?ti0:(l==1)?ti1:(l==2)?ti2:ti3);
    int pos = atomicAdd(&counts[myi], 1);
    tlist[myi*T_ + pos] = (t << 2) | l;
    wlist[myi*T_ + pos] = myw;
  }
}

// ---------------- tiled MFMA GEMM (BK=32, replay-verified sync structure) ----------------
// B consumed directly from fp32 [K,N] with T14 async-STAGE split (loads for
// step kt+1 issued right after barrier-2 of step kt, consumed after the next
// barrier-1). Both barriers intact — verified r5–r7 skeleton.
// MODE 0: y1 = silu(xb @ ws1)              -> bf16 Cb
// MODE 1: out += y1 @ ws2 (split-K atomic) -> f32 Cf
// MODE 2: act[entry] = silu(gather(xb) @ w1[e]) * w   -> bf16
// MODE 3: scratch[entry] = gather(act) @ w2[e]  (plain stores, rows uniquely owned)
// Dense modes: 1-D x-grid, XCD-chunked bijective swizzle (nwg % 8 == 0).
// Routed modes: blockIdx.x = e*NT + nt (all live), blockIdx.y = mt, z = kz.
template<int MODE, int KDIM, int NDIM, int ASTR, int KSPLIT>
__global__ __launch_bounds__(256) void gemm_k(
    const bf16* __restrict__ A, const float* __restrict__ Bf,
    bf16* __restrict__ Cb, float* __restrict__ Cf,
    const int* __restrict__ tlist, const float* __restrict__ wlist,
    const int* __restrict__ counts)
{
  __shared__ __align__(16) char smem[16384];
  char* As = smem;            // 128 rows x 32 k bf16 (64B rows, slot-swizzled)
  char* Bs = smem + 8192;     // slot-major [4][128][16B]
  const int tid = threadIdx.x;

  int mt, nt, e = 0, kz = 0;
  int nrows = T_;
  const int* lst = nullptr;
  const float* Bp = Bf;
  if constexpr (MODE == 2 || MODE == 3) {
    constexpr int NT = NDIM / 128;
    e  = blockIdx.x / NT;
    nt = blockIdx.x % NT;
    mt = blockIdx.y;
    nrows = counts[e];
    if (mt * 128 >= nrows) return;
    lst = tlist + e*T_;
    Bp = Bf + (size_t)e * ((size_t)KDIM * NDIM);
    if constexpr (KSPLIT > 1) kz = blockIdx.z;
  } else {
    constexpr int NWG = 16 * (NDIM / 128);
    constexpr int CPX = NWG / 8;
    int id = blockIdx.x;
    int lg = (id & 7) * CPX + (id >> 3);
    mt = lg & 15;
    nt = lg >> 4;
    if constexpr (KSPLIT > 1) kz = blockIdx.z;
  }
  const int mrow0 = mt*128, ncol0 = nt*128;

  // A staging bases; source pre-swizzled so linear global_load_lds dest + swizzled read agree
  const bf16* abase[2];
  int aoffs[2];
  #pragma unroll
  for (int hh = 0; hh < 2; ++hh) {
    int lidx = hh*256 + tid;
    int row  = lidx >> 2;
    int slog = (lidx & 3) ^ (row & 3);
    aoffs[hh] = slog * 8;
    int ri = mrow0 + row;
    if constexpr (MODE == 2) {
      int tt = (ri < nrows) ? (lst[ri] >> 2) : 0;
      abase[hh] = A + (size_t)tt * ASTR;
    } else if constexpr (MODE == 3) {
      int ar = (ri < nrows) ? lst[ri] : 0;
      abase[hh] = A + (size_t)ar * ASTR;
    } else {
      abase[hh] = A + (size_t)ri * ASTR;
    }
  }

  // B staging: thread covers n = tid&127, k-half bh = tid>>7 (16 rows)
  const int bn = tid & 127;
  const int bh = tid >> 7;
  const float* bsrc0 = Bp + (size_t)(bh * 16) * NDIM + ncol0 + bn;
  char* bdst0 = Bs + (bh*2)*2048 + bn*16;

  const int l  = tid & 63;
  const int wv = tid >> 6;
  const int wr = wv >> 1, wc = wv & 1;
  const int ss = l >> 4;

  f32x4 acc[4][4] = {};

  constexpr int ITERS = KDIM / 32 / KSPLIT;
  static_assert(ITERS % 2 == 0, "K-loop is 2-unrolled");
  const int kt0 = kz * ITERS;
  const int ktend = kt0 + ITERS;

  float vA0,vA1,vA2,vA3,vA4,vA5,vA6,vA7,vA8,vA9,vA10,vA11,vA12,vA13,vA14,vA15;
  float vB0,vB1,vB2,vB3,vB4,vB5,vB6,vB7,vB8,vB9,vB10,vB11,vB12,vB13,vB14,vB15;

#define LOADB(P, KT) do {                                            \
    const float* bs_ = bsrc0 + (size_t)((KT) * 32) * NDIM;           \
    P##0 = bs_[0];            P##1 = bs_[(size_t)1*NDIM];            \
    P##2 = bs_[(size_t)2*NDIM];  P##3 = bs_[(size_t)3*NDIM];         \
    P##4 = bs_[(size_t)4*NDIM];  P##5 = bs_[(size_t)5*NDIM];         \
    P##6 = bs_[(size_t)6*NDIM];  P##7 = bs_[(size_t)7*NDIM];         \
    P##8 = bs_[(size_t)8*NDIM];  P##9 = bs_[(size_t)9*NDIM];         \
    P##10 = bs_[(size_t)10*NDIM]; P##11 = bs_[(size_t)11*NDIM];      \
    P##12 = bs_[(size_t)12*NDIM]; P##13 = bs_[(size_t)13*NDIM];      \
    P##14 = bs_[(size_t)14*NDIM]; P##15 = bs_[(size_t)15*NDIM];      \
  } while (0)

#define WRITEB(P) do {                                               \
    u32x4 lo_, hi_;                                                  \
    lo_[0] = (unsigned)bfb(P##0)  | ((unsigned)bfb(P##1)  << 16);    \
    lo_[1] = (unsigned)bfb(P##2)  | ((unsigned)bfb(P##3)  << 16);    \
    lo_[2] = (unsigned)bfb(P##4)  | ((unsigned)bfb(P##5)  << 16);    \
    lo_[3] = (unsigned)bfb(P##6)  | ((unsigned)bfb(P##7)  << 16);    \
    hi_[0] = (unsigned)bfb(P##8)  | ((unsigned)bfb(P##9)  << 16);    \
    hi_[1] = (unsigned)bfb(P##10) | ((unsigned)bfb(P##11) << 16);    \
    hi_[2] = (unsigned)bfb(P##12) | ((unsigned)bfb(P##13) << 16);    \
    hi_[3] = (unsigned)bfb(P##14) | ((unsigned)bfb(P##15) << 16);    \
    *(u32x4*)(bdst0)        = lo_;                                   \
    *(u32x4*)(bdst0 + 2048) = hi_;                                   \
  } while (0)

#define MFMA_PHASE(KT) do {                                          \
    bf16x8 af[4], bfr[4];                                            \
    _Pragma("unroll")                                                \
    for (int mf = 0; mf < 4; ++mf) {                                 \
      int r = wr*64 + mf*16 + (l & 15);                              \
      af[mf] = *(const bf16x8*)(As + r*64 + ((ss ^ (r & 3)) << 4));  \
    }                                                                \
    _Pragma("unroll")                                                \
    for (int nf = 0; nf < 4; ++nf) {                                 \
      int c = wc*64 + nf*16 + (l & 15);                              \
      bfr[nf] = *(const bf16x8*)(Bs + ss*2048 + c*16);               \
    }                                                                \
    _Pragma("unroll")                                                \
    for (int mf = 0; mf < 4; ++mf)                                   \
      _Pragma("unroll")                                              \
      for (int nf = 0; nf < 4; ++nf)                                 \
        acc[mf][nf] = __builtin_amdgcn_mfma_f32_16x16x32_bf16(af[mf], bfr[nf], acc[mf][nf], 0, 0, 0); \
  } while (0)

#define ADMA(KT) do {                                                \
    _Pragma("unroll")                                                \
    for (int hh = 0; hh < 2; ++hh)                                   \
      gload_lds16(abase[hh] + (KT)*32 + aoffs[hh], As + (hh*256 + tid)*16); \
  } while (0)

  LOADB(vA, kt0);
  for (int kt = kt0; kt < ktend; kt += 2) {
    __syncthreads();
    ADMA(kt);
    WRITEB(vA);
    __syncthreads();
    LOADB(vB, kt + 1);           // flies during MFMA phase
    MFMA_PHASE(kt);

    __syncthreads();
    ADMA(kt + 1);
    WRITEB(vB);
    __syncthreads();
    if (kt + 2 < ktend) LOADB(vA, kt + 2);   // flies during MFMA phase
    MFMA_PHASE(kt + 1);
  }

#undef LOADB
#undef WRITEB
#undef MFMA_PHASE
#undef ADMA

  // epilogue — C/D layout: row=(l>>4)*4+j, col=l&15 within each 16x16 frag
  #pragma unroll
  for (int mf = 0; mf < 4; ++mf) {
    #pragma unroll
    for (int j = 0; j < 4; ++j) {
      const int rloc = wr*64 + mf*16 + (l >> 4)*4 + j;
      const int grow = mrow0 + rloc;
      if constexpr (MODE == 0) {
        #pragma unroll
        for (int nf = 0; nf < 4; ++nf) {
          int col = ncol0 + wc*64 + nf*16 + (l & 15);
          Cb[(size_t)grow * NDIM + col] = (bf16)silu_f(acc[mf][nf][j]);
        }
      } else if constexpr (MODE == 1) {
        #pragma unroll
        for (int nf = 0; nf < 4; ++nf) {
          int col = ncol0 + wc*64 + nf*16 + (l & 15);
          atomicAdd(Cf + (size_t)grow * NDIM + col, acc[mf][nf][j]);
        }
      } else if constexpr (MODE == 2) {
        if (grow < nrows) {
          int entry = lst[grow];
          float wg = wlist[e*T_ + grow];
          #pragma unroll
          for (int nf = 0; nf < 4; ++nf) {
            int col = ncol0 + wc*64 + nf*16 + (l & 15);
            Cb[(size_t)entry * NDIM + col] = (bf16)(silu_f(acc[mf][nf][j]) * wg);
          }
        }
      } else {
        if (grow < nrows) {
          int entry = lst[grow];
          #pragma unroll
          for (int nf = 0; nf < 4; ++nf) {
            int col = ncol0 + wc*64 + nf*16 + (l & 15);
            Cf[(size_t)entry * H_ + col] = acc[mf][nf][j];
          }
        }
      }
    }
  }
}

extern "C" void kernel_launch(void* const* d_in, const int* in_sizes, int n_in,
                              void* d_out, int out_size, void* d_ws, size_t ws_size,
                              hipStream_t stream) {
  const float* x   = (const float*)d_in[0];
  const float* gw  = (const float*)d_in[1];
  const float* w1  = (const float*)d_in[2];
  const float* w2  = (const float*)d_in[3];
  const float* ws1 = (const float*)d_in[4];
  const float* ws2 = (const float*)d_in[5];
  float* out    = (float*)d_out;
  float* logits = out + (size_t)T_ * H_;

  char* ws = (char*)d_ws;
  const size_t off_xb   = 0;
  const size_t off_y1   = off_xb  + (size_t)T_ * H_ * 2;
  const size_t off_act  = off_y1  + (size_t)T_ * I_ * 2;
  const size_t off_cnt  = off_act + (size_t)T_ * 4 * M_ * 2;
  const size_t off_tl   = off_cnt + 256;
  const size_t off_wl   = off_tl  + (size_t)E_ * T_ * 4;
  const size_t off_sc   = off_wl  + (size_t)E_ * T_ * 4;   // fp32 [4T][H] = 67 MB

  const bf16* xb = (const bf16*)(ws + off_xb);
  bf16* y1  = (bf16*)(ws + off_y1);
  bf16* act = (bf16*)(ws + off_act);
  int*  counts = (int*)(ws + off_cnt);
  int*  tlist  = (int*)(ws + off_tl);
  float* wlist = (float*)(ws + off_wl);
  float* scratch = (float*)(ws + off_sc);

  prep_k<<<4096, 256, 0, stream>>>(out, counts);
  router_k<<<T_, 64, 0, stream>>>(x, gw, logits, counts, tlist, wlist);
  cvt_k<<<2048, 256, 0, stream>>>(x, (unsigned short*)(ws + off_xb));

  gemm_k<0, 2048, 8192, 2048, 1><<<dim3(1024), 256, 0, stream>>>(
      xb, ws1, y1, nullptr, nullptr, nullptr, nullptr);
  gemm_k<1, 8192, 2048, 8192, 4><<<dim3(256, 1, 4), 256, 0, stream>>>(
      y1, ws2, nullptr, out, nullptr, nullptr, nullptr);
  gemm_k<2, 2048, 1408, 2048, 1><<<dim3(11*E_, 16), 256, 0, stream>>>(
      xb, w1, act, nullptr, tlist, wlist, counts);
  gemm_k<3, 1408, 2048, 1408, 1><<<dim3(16*E_, 16), 256, 0, stream>>>(
      act, w2, nullptr, scratch, tlist, nullptr, counts);
  combine_k<<<4096, 256, 0, stream>>>(scratch, out);
}